// Round 5
// baseline (362.474 us; speedup 1.0000x reference)
//
#include <hip/hip_runtime.h>
#include <hip/hip_bf16.h>

#define B_ 2
#define S_ 2048
#define D_ 768
#define E_ 8
#define F_ 3072
#define NT (B_*S_)            // 4096 tokens
#define BM 256
#define BN 128
#define BK 128
#define MAXT 24               // max tiles at BM=256: <= 16+7

typedef __attribute__((ext_vector_type(8))) short bf16x8;
typedef __attribute__((ext_vector_type(4))) float f32x4;
typedef __attribute__((ext_vector_type(8))) unsigned short u16x8;

__device__ __forceinline__ unsigned short f2bf(float f){
  __hip_bfloat16 h = __float2bfloat16(f);
  return *reinterpret_cast<unsigned short*>(&h);
}

__device__ __forceinline__ void gll16(const void* g, void* l){
  __builtin_amdgcn_global_load_lds((const __attribute__((address_space(1))) unsigned int*)g,
                                   (__attribute__((address_space(3))) unsigned int*)l,
                                   16, 0, 0);
}

// ---------------------------------------------------------------------------
// Router: 64 tokens/block (4 waves x 16). fp32 logits via butterfly reduce,
// softmax+argmax on lane 0, then a single-wave ballot pass builds bucket
// positions with 8 global atomics per block (two-level counting).
// ---------------------------------------------------------------------------
__global__ __launch_bounds__(256) void router_kernel(
    const float* __restrict__ x, const float* __restrict__ wr,
    float* __restrict__ logits_out, float* __restrict__ idx_out,
    float* __restrict__ probs, int* __restrict__ counts, int* __restrict__ bucket)
{
  __shared__ int sbest[64];
  const int wave = threadIdx.x >> 6, lane = threadIdx.x & 63;
  const int tbase = blockIdx.x * 64 + wave * 16;

  for (int it = 0; it < 16; ++it){
    const int token = tbase + it;
    const float* xp = x + (size_t)token * D_;
    float acc[E_] = {0.f,0.f,0.f,0.f,0.f,0.f,0.f,0.f};
    #pragma unroll
    for (int i = 0; i < 12; ++i){
      const int d = lane + i*64;
      const float v = xp[d];
      const float4 w0 = *(const float4*)(wr + d*8);
      const float4 w1v = *(const float4*)(wr + d*8 + 4);
      acc[0] += v*w0.x; acc[1] += v*w0.y; acc[2] += v*w0.z; acc[3] += v*w0.w;
      acc[4] += v*w1v.x; acc[5] += v*w1v.y; acc[6] += v*w1v.z; acc[7] += v*w1v.w;
    }
    #pragma unroll
    for (int j = 0; j < E_; ++j){
      float a = acc[j];
      for (int off = 32; off > 0; off >>= 1) a += __shfl_xor(a, off);
      acc[j] = a;
    }
    if (lane == 0){
      float m = acc[0];
      #pragma unroll
      for (int j = 1; j < E_; ++j) m = fmaxf(m, acc[j]);
      float p[E_]; float s = 0.f;
      #pragma unroll
      for (int j = 0; j < E_; ++j){ p[j] = expf(acc[j] - m); s += p[j]; }
      const float inv = 1.0f / s;
      int best = 0; float bp = p[0]*inv;
      #pragma unroll
      for (int j = 1; j < E_; ++j){ const float pj = p[j]*inv; if (pj > bp){ bp = pj; best = j; } }
      float* lo = logits_out + (size_t)token * E_;
      #pragma unroll
      for (int j = 0; j < E_; ++j) lo[j] = acc[j];
      idx_out[token] = (float)best;
      probs[token] = bp;
      sbest[wave*16 + it] = best;
    }
  }
  __syncthreads();
  if (threadIdx.x < 64){               // wave 0 only
    const int l = threadIdx.x;
    const int b = sbest[l];
    unsigned long long m = 0;
    #pragma unroll
    for (int e2 = 0; e2 < E_; ++e2){
      const unsigned long long me = __ballot(b == e2);
      if (b == e2) m = me;
    }
    const int rank = __popcll(m & ((1ull << l) - 1ull));
    const int leader = __ffsll((long long)m) - 1;
    int baseval = 0;
    if (l == leader) baseval = atomicAdd(&counts[b], __popcll(m));
    baseval = __shfl(baseval, leader);
    bucket[b * NT + baseval + rank] = blockIdx.x * 64 + l;
  }
}

// ---------------------------------------------------------------------------
// meta[0]=ntiles, meta[1+e]=compact row offset, meta[16+i]=(e<<16)|mt
// ---------------------------------------------------------------------------
__global__ void build_tiles(const int* __restrict__ counts, int* __restrict__ meta)
{
  if (threadIdx.x == 0 && blockIdx.x == 0){
    int off = 0, n = 0;
    for (int e = 0; e < E_; ++e){
      const int c = counts[e];
      meta[1+e] = off;
      const int t = (c + BM - 1) / BM;
      for (int mtt = 0; mtt < t; ++mtt){ meta[16 + n] = (e << 16) | mtt; ++n; }
      off += c;
    }
    meta[0] = n;
  }
}

// ---------------------------------------------------------------------------
// Gather x rows into expert-compact order, fp32 -> bf16. One wave per row.
// ---------------------------------------------------------------------------
__global__ __launch_bounds__(256) void gather_cvt(
    const float* __restrict__ x, const int* __restrict__ bucket,
    const int* __restrict__ meta, unsigned short* __restrict__ Ac)
{
  const int wave = threadIdx.x >> 6, lane = threadIdx.x & 63;
  const int i = blockIdx.x * 4 + wave;      // compact row
  int e = 0;
  #pragma unroll
  for (int k = 1; k < E_; ++k) if (meta[1+k] <= i) e = k;
  const int tok = bucket[e * NT + (i - meta[1+e])];
  const float* src = x + (size_t)tok * D_;
  unsigned short* dst = Ac + (size_t)i * D_;
  #pragma unroll
  for (int p = 0; p < 3; ++p){
    const float4 v = *(const float4*)(src + p*256 + lane*4);
    ushort4 o;
    o.x = f2bf(v.x); o.y = f2bf(v.y); o.z = f2bf(v.z); o.w = f2bf(v.w);
    *(ushort4*)(dst + p*256 + lane*4) = o;
  }
}

// ---------------------------------------------------------------------------
// Transpose + fp32->bf16: in [E][R][C] f32 -> out [E][C][R] bf16
// ---------------------------------------------------------------------------
__global__ __launch_bounds__(256) void transpose_cvt(
    const float* __restrict__ in, unsigned short* __restrict__ outp, int R, int C)
{
  __shared__ float tile[64][65];
  const int e = blockIdx.z;
  const int r0 = blockIdx.y << 6, c0 = blockIdx.x << 6;
  const float* src = in + (size_t)e * R * C;
  unsigned short* dst = outp + (size_t)e * R * C;
  const int tid = threadIdx.x;
  {
    const int lr = tid >> 4, lc = (tid & 15) << 2;
    #pragma unroll
    for (int rr = 0; rr < 4; ++rr){
      const int row = (rr << 4) + lr;
      const float4 v = *(const float4*)(src + (size_t)(r0 + row) * C + c0 + lc);
      tile[row][lc+0] = v.x; tile[row][lc+1] = v.y;
      tile[row][lc+2] = v.z; tile[row][lc+3] = v.w;
    }
  }
  __syncthreads();
  {
    const int wrr = tid >> 3, wcc = (tid & 7) << 3;
    #pragma unroll
    for (int it = 0; it < 2; ++it){
      const int crow = (it << 5) + wrr;
      u16x8 o;
      #pragma unroll
      for (int j = 0; j < 8; ++j) o[j] = f2bf(tile[wcc + j][crow]);
      *(u16x8*)(dst + (size_t)(c0 + crow) * R + r0 + wcc) = o;
    }
  }
}

// ---------------------------------------------------------------------------
// Grouped GEMM: 256x128 tile, BK=128, single-buffer (96 KB LDS), 8 waves
// (wave tile 64x64, 4M x 2N). m97 2-barrier structure, deep in-flight staging.
// XOR-swizzle (row&15)<<4 on 256 B LDS rows, inverse-swizzled global source.
// XCD-chunked bijective block remap, nt-fastest.
// RELU=1: A=Ac compact, out=relu->bf16 h1c compact.
// RELU=0: A=h1c, out += p * acc via fp32 atomicAdd (split-K), scatter by token.
// ---------------------------------------------------------------------------
template<int KC, int KTOT, int NCOLS, bool RELU, int NSPLIT>
__global__ __launch_bounds__(512) void gemm_g(
    const unsigned short* __restrict__ Ac, const unsigned short* __restrict__ Bt,
    const int* __restrict__ counts, const int* __restrict__ bucket,
    const int* __restrict__ meta, const float* __restrict__ probs,
    unsigned short* __restrict__ h1out, float* __restrict__ fout)
{
  __shared__ unsigned short As[BM*BK];   // 64 KB
  __shared__ unsigned short Bs[BN*BK];   // 32 KB

  // bijective XCD chunk remap (m204), nt-fastest ordering
  const int nwg = gridDim.x * gridDim.y * gridDim.z;
  const int orig = ((int)blockIdx.z * gridDim.y + blockIdx.y) * gridDim.x + blockIdx.x;
  const int q = nwg >> 3, r = nwg & 7;
  const int xcd = orig & 7, jj = orig >> 3;
  const int wgid = (xcd < r ? xcd*(q+1) : r*(q+1) + (xcd - r)*q) + jj;
  constexpr int NTC = NCOLS / BN;
  const int nt = wgid % NTC;
  const int rest = wgid / NTC;
  const int ks = (NSPLIT > 1) ? (rest % NSPLIT) : 0;
  const int tile = (NSPLIT > 1) ? (rest / NSPLIT) : rest;
  if (tile >= meta[0]) return;

  const int em = meta[16 + tile];
  const int e = em >> 16, mt = em & 0xffff;
  const int cnt = counts[e], off_e = meta[1+e];
  const int rbase = mt * BM;
  const int fbase = nt * BN;
  const int tid = threadIdx.x, wave = tid >> 6, lane = tid & 63;
  const int rsub = lane >> 4;            // 0..3 row within 4-row chunk
  const int c16 = lane & 15;             // 16B slot within 256B row
  const int cm1 = cnt - 1;

  const char* Asrc[8]; const char* Bsrc[4];
  #pragma unroll
  for (int c = 0; c < 8; ++c){
    const int row = ((wave + (c << 3)) << 2) + rsub;     // 0..255
    int gr = rbase + row; if (gr > cm1) gr = cm1;
    Asrc[c] = (const char*)(Ac + (size_t)(off_e + gr) * KTOT + ks * KC)
              + ((c16 ^ (row & 15)) << 4);
  }
  #pragma unroll
  for (int c = 0; c < 4; ++c){
    const int row = ((wave + (c << 3)) << 2) + rsub;     // 0..127
    Bsrc[c] = (const char*)(Bt + ((size_t)e * NCOLS + fbase + row) * KTOT + ks * KC)
              + ((c16 ^ (row & 15)) << 4);
  }

  const int wr = (wave >> 1) << 6;       // 4 M-waves
  const int wc = (wave & 1) << 6;        // 2 N-waves
  const int lo16 = lane & 15, hi = lane >> 4;
  f32x4 acc[4][4] = {};
  constexpr int NKT = KC / BK;

  for (int kt = 0; kt < NKT; ++kt){
    const int kb = kt * (BK * 2);        // 256 B per row per K-tile
    #pragma unroll
    for (int c = 0; c < 8; ++c)
      gll16(Asrc[c] + kb, (char*)As + ((wave + (c << 3)) << 10));
    #pragma unroll
    for (int c = 0; c < 4; ++c)
      gll16(Bsrc[c] + kb, (char*)Bs + ((wave + (c << 3)) << 10));
    __syncthreads();                     // drains vmcnt -> tile ready
    #pragma unroll
    for (int kf = 0; kf < 4; ++kf){
      const int ko = (kf << 6) + (hi << 4);
      bf16x8 af[4], bv[4];
      #pragma unroll
      for (int mf = 0; mf < 4; ++mf){
        const int row = wr + (mf << 4) + lo16;
        af[mf] = *(const bf16x8*)((const char*)As + row * 256 + (ko ^ ((row & 15) << 4)));
      }
      #pragma unroll
      for (int nf = 0; nf < 4; ++nf){
        const int col = wc + (nf << 4) + lo16;
        bv[nf] = *(const bf16x8*)((const char*)Bs + col * 256 + (ko ^ ((col & 15) << 4)));
      }
      #pragma unroll
      for (int mf = 0; mf < 4; ++mf)
        #pragma unroll
        for (int nf = 0; nf < 4; ++nf)
          acc[mf][nf] = __builtin_amdgcn_mfma_f32_16x16x32_bf16(af[mf], bv[nf], acc[mf][nf], 0, 0, 0);
    }
    __syncthreads();                     // LDS reads done before next stage
  }

  // ---- epilogue ----
  const int rem = cnt - rbase;
  #pragma unroll
  for (int mf = 0; mf < 4; ++mf){
    #pragma unroll
    for (int j = 0; j < 4; ++j){
      const int rr2 = wr + (mf << 4) + (hi << 2) + j;
      if (rr2 < rem){
        if constexpr (RELU){
          const size_t crow = (size_t)(off_e + rbase + rr2);
          #pragma unroll
          for (int nf = 0; nf < 4; ++nf){
            float v = acc[mf][nf][j];
            v = v > 0.f ? v : 0.f;
            h1out[crow * NCOLS + fbase + wc + (nf << 4) + lo16] = f2bf(v);
          }
        } else {
          const int tok = bucket[e * NT + rbase + rr2];
          const float p = probs[tok];
          #pragma unroll
          for (int nf = 0; nf < 4; ++nf)
            atomicAdd(&fout[(size_t)tok * NCOLS + fbase + wc + (nf << 4) + lo16],
                      p * acc[mf][nf][j]);
        }
      }
    }
  }
}

// ---------------------------------------------------------------------------
extern "C" void kernel_launch(void* const* d_in, const int* in_sizes, int n_in,
                              void* d_out, int out_size, void* d_ws, size_t ws_size,
                              hipStream_t stream)
{
  const float* x  = (const float*)d_in[0];
  const float* wr = (const float*)d_in[1];
  const float* w1 = (const float*)d_in[2];
  const float* w2 = (const float*)d_in[3];
  float* out = (float*)d_out;

  constexpr size_t OUT_L = (size_t)NT * D_;
  constexpr size_t OUT_I = OUT_L + (size_t)NT * E_;

  char* ws = (char*)d_ws;
  int*            counts = (int*)ws;
  int*            meta   = (int*)(ws + 256);
  float*          probs  = (float*)(ws + 1024);
  int*            bucket = (int*)(ws + (32u << 10));
  unsigned short* Ac     = (unsigned short*)(ws + (256u << 10));  // 6 MB compact x bf16
  unsigned short* w1t    = (unsigned short*)(ws + (8ull  << 20)); // [E][F][D] bf16
  unsigned short* w2t    = (unsigned short*)(ws + (48ull << 20)); // [E][D][F] bf16
  unsigned short* h1c    = (unsigned short*)(ws + (88ull << 20)); // compact [NT][F] bf16

  hipMemsetAsync(counts, 0, E_ * sizeof(int), stream);
  hipMemsetAsync(out, 0, OUT_L * sizeof(float), stream);  // split-K accumulator

  router_kernel<<<dim3(NT/64), dim3(256), 0, stream>>>(
      x, wr, out + OUT_L, out + OUT_I, probs, counts, bucket);

  build_tiles<<<dim3(1), dim3(64), 0, stream>>>(counts, meta);

  gather_cvt<<<dim3(NT/4), dim3(256), 0, stream>>>(x, bucket, meta, Ac);

  transpose_cvt<<<dim3(F_/64, D_/64, E_), dim3(256), 0, stream>>>(w1, w1t, D_, F_);
  transpose_cvt<<<dim3(D_/64, F_/64, E_), dim3(256), 0, stream>>>(w2, w2t, F_, D_);

  gemm_g<D_, D_, F_, true, 1><<<dim3(F_/BN, MAXT), dim3(512), 0, stream>>>(
      Ac, w1t, counts, bucket, meta, nullptr, h1c, nullptr);

  gemm_g<F_/2, F_, D_, false, 2><<<dim3(D_/BN, MAXT, 2), dim3(512), 0, stream>>>(
      h1c, w2t, counts, bucket, meta, probs, nullptr, out);
}